// Round 1
// baseline (2412.539 us; speedup 1.0000x reference)
//
#include <hip/hip_runtime.h>
#include <math.h>

// Problem constants (ConformerEncoderLayer, T=512 B=16 C=512 H=8 d=64 DFF=2048 K=31)
#define T_SEQ 512
#define B_SZ  16
#define C_DIM 512
#define NH    8
#define HD    64
#define DFF_  2048
#define NROWS (T_SEQ * B_SZ)   // 8192 rows of (t*B+b)
#define BCHUNK 4               // attention batches per chunk (scores buffer = BCHUNK*8*512*512 f32)
#define EPS_BN 1.2840254166877414f  // exp(0.25)

__device__ __forceinline__ float sigmoidf_(float x) { return 1.f / (1.f + __expf(-x)); }
__device__ __forceinline__ float dswishf_(float x)  { return x * sigmoidf_(x - 1.f); }

// ---------------------------------------------------------------------------
// Generic f32 GEMM: out(N,M) = [res +] act(A(N,K) @ W(M,K)^T + bias)
// 64x64 tile, BK=16, 256 threads, 4x4 accum per thread. N may be ragged.
// ---------------------------------------------------------------------------
template <int ACT, bool HAS_RES>
__global__ __launch_bounds__(256) void gemm_bt(
    const float* __restrict__ A, const float* __restrict__ W,
    const float* __restrict__ bias, const float* __restrict__ res,
    float* __restrict__ out, int N, int K, int M)
{
    __shared__ float As[16][64];
    __shared__ float Ws[16][64];
    const int tid = threadIdx.x;
    const int m0 = blockIdx.x * 64;
    const int n0 = blockIdx.y * 64;
    const int tx = tid & 15, ty = tid >> 4;
    const int ln = tid >> 2;            // 0..63
    const int lk = (tid & 3) << 2;      // 0,4,8,12
    float acc[4][4] = {};

    for (int k0 = 0; k0 < K; k0 += 16) {
        const int an = n0 + ln;
        float4 av = make_float4(0.f, 0.f, 0.f, 0.f);
        if (an < N) av = *(const float4*)(A + (size_t)an * K + k0 + lk);
        As[lk + 0][ln] = av.x; As[lk + 1][ln] = av.y;
        As[lk + 2][ln] = av.z; As[lk + 3][ln] = av.w;
        const float4 wv = *(const float4*)(W + (size_t)(m0 + ln) * K + k0 + lk);
        Ws[lk + 0][ln] = wv.x; Ws[lk + 1][ln] = wv.y;
        Ws[lk + 2][ln] = wv.z; Ws[lk + 3][ln] = wv.w;
        __syncthreads();
#pragma unroll
        for (int kk = 0; kk < 16; ++kk) {
            const float4 a = *(const float4*)&As[kk][ty << 2];
            const float4 b = *(const float4*)&Ws[kk][tx << 2];
            const float aa[4] = {a.x, a.y, a.z, a.w};
            const float bb[4] = {b.x, b.y, b.z, b.w};
#pragma unroll
            for (int i = 0; i < 4; ++i)
#pragma unroll
                for (int j = 0; j < 4; ++j) acc[i][j] += aa[i] * bb[j];
        }
        __syncthreads();
    }

#pragma unroll
    for (int i = 0; i < 4; ++i) {
        const int n = n0 + (ty << 2) + i;
        if (n >= N) return;
        float* orow = out + (size_t)n * M + m0 + (tx << 2);
        const float* rrow = res + (size_t)n * M + m0 + (tx << 2);
#pragma unroll
        for (int j = 0; j < 4; ++j) {
            const int m = m0 + (tx << 2) + j;
            float v = acc[i][j] + (bias ? bias[m] : 0.f);
            if (ACT == 1) v = dswishf_(v);
            if (HAS_RES) v += rrow[j];
            orow[j] = v;
        }
    }
}

// ---------------------------------------------------------------------------
// Attention scores: scores[bhl][t][s] = sum_d (q*0.125+u)[t,d]*k[s,d]
//                                     + sum_d (q*0.125+v)[t,d]*p[511-t+s,d]
// One block: 32 t-rows x 64 s-cols for one (b,h). rel-shift handled by a
// shifted p-tile of 96 rows (jbase = s0 - t0 + 480, local row = 31 - tt + ss).
// ---------------------------------------------------------------------------
__global__ __launch_bounds__(256) void attn_scores(
    const float* __restrict__ qkv, const float* __restrict__ pmat,
    const float* __restrict__ ub, const float* __restrict__ vb,
    float* __restrict__ scores, int b0)
{
    __shared__ float qu[32][65], qv[32][65], ks[64][65], ps[96][65];
    const int tid = threadIdx.x;
    const int s0 = blockIdx.x * 64;
    const int t0 = blockIdx.y * 32;
    const int bhl = blockIdx.z;           // local (b,h): bl*8+h
    const int bl = bhl >> 3, h = bhl & 7;
    const int b = b0 + bl;
    const int jbase = s0 - t0 + 480;

    for (int e = tid; e < 32 * 64; e += 256) {
        const int tt = e >> 6, d = e & 63;
        const float q = qkv[((size_t)(t0 + tt) * B_SZ + b) * 1536 + h * 64 + d] * 0.125f;
        qu[tt][d] = q + ub[h * 64 + d];
        qv[tt][d] = q + vb[h * 64 + d];
    }
    for (int e = tid; e < 64 * 64; e += 256) {
        const int ss = e >> 6, d = e & 63;
        ks[ss][d] = qkv[((size_t)(s0 + ss) * B_SZ + b) * 1536 + 512 + h * 64 + d];
    }
    for (int e = tid; e < 96 * 64; e += 256) {
        const int jl = e >> 6, d = e & 63;
        const int j = jbase + jl;
        ps[jl][d] = (j < 1023) ? pmat[(size_t)j * 512 + h * 64 + d] : 0.f;
    }
    __syncthreads();

    const int tt0 = (tid >> 4) << 1;      // 0,2,..,30
    const int ss0 = (tid & 15) << 2;      // 0,4,..,60
    float acc0[4] = {}, acc1[4] = {};
#pragma unroll 4
    for (int d = 0; d < 64; ++d) {
        const float a0u = qu[tt0][d], a1u = qu[tt0 + 1][d];
        const float a0v = qv[tt0][d], a1v = qv[tt0 + 1][d];
#pragma unroll
        for (int j = 0; j < 4; ++j) {
            const float bk = ks[ss0 + j][d];
            const int r = 31 - tt0 + ss0 + j;   // in [1,94]; r-1 in [0,93]
            acc0[j] += a0u * bk + a0v * ps[r][d];
            acc1[j] += a1u * bk + a1v * ps[r - 1][d];
        }
    }
    const size_t base = ((size_t)bhl * 512 + t0 + tt0) * 512 + s0 + ss0;
#pragma unroll
    for (int j = 0; j < 4; ++j) {
        scores[base + j] = acc0[j];
        scores[base + 512 + j] = acc1[j];
    }
}

// One wave per 512-long row; 4 rows per block.
__global__ __launch_bounds__(256) void softmax_rows(float* __restrict__ s)
{
    const int row = blockIdx.x * 4 + (threadIdx.x >> 6);
    const int lane = threadIdx.x & 63;
    float* r = s + (size_t)row * 512;
    float v[8];
    float mx = -1e30f;
#pragma unroll
    for (int j = 0; j < 8; ++j) { v[j] = r[lane + (j << 6)]; mx = fmaxf(mx, v[j]); }
#pragma unroll
    for (int o = 32; o > 0; o >>= 1) mx = fmaxf(mx, __shfl_xor(mx, o, 64));
    float sum = 0.f;
#pragma unroll
    for (int j = 0; j < 8; ++j) { v[j] = __expf(v[j] - mx); sum += v[j]; }
#pragma unroll
    for (int o = 32; o > 0; o >>= 1) sum += __shfl_xor(sum, o, 64);
    const float inv = 1.f / sum;
#pragma unroll
    for (int j = 0; j < 8; ++j) r[lane + (j << 6)] = v[j] * inv;
}

// ao[t, b, h*64+d] = sum_s attn[bhl,t,s] * v[s,b,h,d]; 64(t)x64(d) tile.
__global__ __launch_bounds__(256) void attn_pv(
    const float* __restrict__ scores, const float* __restrict__ qkv,
    float* __restrict__ ao, int b0)
{
    __shared__ float At[16][64];
    __shared__ float Vs[16][64];
    const int tid = threadIdx.x;
    const int t0 = blockIdx.x * 64;
    const int bhl = blockIdx.y;
    const int bl = bhl >> 3, h = bhl & 7;
    const int b = b0 + bl;
    const int tx = tid & 15, ty = tid >> 4;
    const int ln = tid >> 2, lk = (tid & 3) << 2;
    const int vs_s = tid >> 4, vs_d = (tid & 15) << 2;
    float acc[4][4] = {};
    const float* arow = scores + ((size_t)bhl * 512 + t0 + ln) * 512 + lk;

    for (int k0 = 0; k0 < 512; k0 += 16) {
        const float4 av = *(const float4*)(arow + k0);
        At[lk + 0][ln] = av.x; At[lk + 1][ln] = av.y;
        At[lk + 2][ln] = av.z; At[lk + 3][ln] = av.w;
        const float4 vv = *(const float4*)(qkv + ((size_t)(k0 + vs_s) * B_SZ + b) * 1536 + 1024 + h * 64 + vs_d);
        *(float4*)&Vs[vs_s][vs_d] = vv;
        __syncthreads();
#pragma unroll
        for (int kk = 0; kk < 16; ++kk) {
            const float4 a = *(const float4*)&At[kk][ty << 2];
            const float4 bvv = *(const float4*)&Vs[kk][tx << 2];
            const float aa[4] = {a.x, a.y, a.z, a.w};
            const float bb[4] = {bvv.x, bvv.y, bvv.z, bvv.w};
#pragma unroll
            for (int i = 0; i < 4; ++i)
#pragma unroll
                for (int j = 0; j < 4; ++j) acc[i][j] += aa[i] * bb[j];
        }
        __syncthreads();
    }
#pragma unroll
    for (int i = 0; i < 4; ++i) {
        const int t = t0 + (ty << 2) + i;
        float* orow = ao + ((size_t)t * B_SZ + b) * 512 + h * 64 + (tx << 2);
#pragma unroll
        for (int j = 0; j < 4; ++j) orow[j] = acc[i][j];
    }
}

// GLU over channel halves of (n, 1024) rows.
__global__ __launch_bounds__(256) void glu_k(const float* __restrict__ in, float* __restrict__ out)
{
    const int idx = blockIdx.x * 256 + threadIdx.x;
    const int n = idx >> 9, c = idx & 511;
    const float a = in[(size_t)n * 1024 + c];
    const float g = in[(size_t)n * 1024 + 512 + c];
    out[idx] = a * sigmoidf_(g);
}

// Causal depthwise conv (K=31, left-pad 30) + DoubleSwish. Layout (t,b,c).
__global__ __launch_bounds__(256) void dwconv_k(
    const float* __restrict__ g, const float* __restrict__ w,
    const float* __restrict__ bb, float* __restrict__ out)
{
    const int idx = blockIdx.x * 256 + threadIdx.x;
    const int c = idx & 511;
    const int tb = idx >> 9;
    const int b = tb & 15, t = tb >> 4;
    float acc = bb[c];
#pragma unroll
    for (int j = 0; j < 31; ++j) {
        const int tt = t - 30 + j;
        if (tt >= 0) acc += g[((size_t)tt * B_SZ + b) * 512 + c] * w[c * 31 + j];
    }
    out[idx] = dswishf_(acc);
}

// BasicNorm: x *= rsqrt(mean_c(x^2) + exp(0.25)); one wave per row.
__global__ __launch_bounds__(256) void norm_k(float* __restrict__ x)
{
    const int row = blockIdx.x * 4 + (threadIdx.x >> 6);
    const int lane = threadIdx.x & 63;
    float* r = x + (size_t)row * 512;
    float v[8];
    float ss = 0.f;
#pragma unroll
    for (int j = 0; j < 8; ++j) { v[j] = r[lane + (j << 6)]; ss += v[j] * v[j]; }
#pragma unroll
    for (int o = 32; o > 0; o >>= 1) ss += __shfl_xor(ss, o, 64);
    const float scale = rsqrtf(ss * (1.f / 512.f) + EPS_BN);
#pragma unroll
    for (int j = 0; j < 8; ++j) r[lane + (j << 6)] = v[j] * scale;
}

// ---------------------------------------------------------------------------
extern "C" void kernel_launch(void* const* d_in, const int* in_sizes, int n_in,
                              void* d_out, int out_size, void* d_ws, size_t ws_size,
                              hipStream_t stream)
{
    const float* src   = (const float*)d_in[0];
    const float* pos   = (const float*)d_in[1];
    const float* fm_w1 = (const float*)d_in[2];
    const float* fm_b1 = (const float*)d_in[3];
    const float* fm_w2 = (const float*)d_in[4];
    const float* fm_b2 = (const float*)d_in[5];
    const float* f_w1  = (const float*)d_in[6];
    const float* f_b1  = (const float*)d_in[7];
    const float* f_w2  = (const float*)d_in[8];
    const float* f_b2  = (const float*)d_in[9];
    const float* ipw   = (const float*)d_in[10];
    const float* ipb   = (const float*)d_in[11];
    const float* opw   = (const float*)d_in[12];
    const float* opb   = (const float*)d_in[13];
    const float* lpw   = (const float*)d_in[14];
    const float* pbu   = (const float*)d_in[15];
    const float* pbv   = (const float*)d_in[16];
    const float* cpw1  = (const float*)d_in[17];
    const float* cpb1  = (const float*)d_in[18];
    const float* cdw   = (const float*)d_in[19];
    const float* cdb   = (const float*)d_in[20];
    const float* cpw2  = (const float*)d_in[21];
    const float* cpb2  = (const float*)d_in[22];

    float* x  = (float*)d_out;            // running activation (8192 x 512)
    float* ws = (float*)d_ws;
    // ws layout (floats), total 42,467,328 floats = ~170 MB
    float* h    = ws;                      // 16,777,216  (8192 x 2048) FFN hidden / conv dw out
    float* qkvb = h + 16777216;            // 12,582,912  (8192 x 1536) qkv / conv pw1 out
    float* pm   = qkvb + 12582912;         //    524,288  (1023 x 512) projected pos emb
    float* sc   = pm + 524288;             //  8,388,608  (BCHUNK*8 x 512 x 512) scores chunk
    float* ao   = sc + 8388608;            //  4,194,304  (8192 x 512) attn out / GLU out

    const dim3 blk(256);

    // 1) macaron FFN: x = src + W2 @ dswish(W1 @ src)
    gemm_bt<1, false><<<dim3(DFF_ / 64, NROWS / 64), blk, 0, stream>>>(src, fm_w1, fm_b1, nullptr, h, NROWS, 512, DFF_);
    gemm_bt<0, true><<<dim3(512 / 64, NROWS / 64), blk, 0, stream>>>(h, fm_w2, fm_b2, src, x, NROWS, DFF_, 512);

    // 2) qkv projection and positional projection
    gemm_bt<0, false><<<dim3(1536 / 64, NROWS / 64), blk, 0, stream>>>(x, ipw, ipb, nullptr, qkvb, NROWS, 512, 1536);
    gemm_bt<0, false><<<dim3(512 / 64, 16), blk, 0, stream>>>(pos, lpw, nullptr, nullptr, pm, 1023, 512, 512);

    // 3) rel-pos attention, chunked over batch (BCHUNK batches per pass)
    for (int bc = 0; bc < B_SZ / BCHUNK; ++bc) {
        attn_scores<<<dim3(8, 16, BCHUNK * NH), blk, 0, stream>>>(qkvb, pm, pbu, pbv, sc, bc * BCHUNK);
        softmax_rows<<<dim3(BCHUNK * NH * 512 / 4), blk, 0, stream>>>(sc);
        attn_pv<<<dim3(8, BCHUNK * NH), blk, 0, stream>>>(sc, qkvb, ao, bc * BCHUNK);
    }

    // 4) out projection (residual into x)
    gemm_bt<0, true><<<dim3(8, 128), blk, 0, stream>>>(ao, opw, opb, x, x, NROWS, 512, 512);

    // 5) conv module: pw1 -> GLU -> causal dwconv + dswish -> pw2 (residual)
    gemm_bt<0, false><<<dim3(16, 128), blk, 0, stream>>>(x, cpw1, cpb1, nullptr, qkvb, NROWS, 512, 1024);
    glu_k<<<dim3(NROWS * 512 / 256), blk, 0, stream>>>(qkvb, ao);
    dwconv_k<<<dim3(NROWS * 512 / 256), blk, 0, stream>>>(ao, cdw, cdb, h);
    gemm_bt<0, true><<<dim3(8, 128), blk, 0, stream>>>(h, cpw2, cpb2, x, x, NROWS, 512, 512);

    // 6) second FFN
    gemm_bt<1, false><<<dim3(32, 128), blk, 0, stream>>>(x, f_w1, f_b1, nullptr, h, NROWS, 512, DFF_);
    gemm_bt<0, true><<<dim3(8, 128), blk, 0, stream>>>(h, f_w2, f_b2, x, x, NROWS, DFF_, 512);

    // 7) BasicNorm
    norm_k<<<dim3(NROWS / 4), blk, 0, stream>>>(x);
}

// Round 5
// 1268.962 us; speedup vs baseline: 1.9012x; 1.9012x over previous
//
#include <hip/hip_runtime.h>
#include <math.h>

// Problem constants (ConformerEncoderLayer, T=512 B=16 C=512 H=8 d=64 DFF=2048 K=31)
#define T_SEQ 512
#define B_SZ  16
#define C_DIM 512
#define NH    8
#define HD    64
#define DFF_  2048
#define NROWS (T_SEQ * B_SZ)   // 8192 rows of (t*B+b)
#define BCHUNK 4               // attention batches per chunk
#define EPS_BN 1.2840254166877414f  // exp(0.25)

typedef unsigned short u16;
typedef __attribute__((ext_vector_type(8))) short bf16x8;
typedef __attribute__((ext_vector_type(4))) float f32x4;

__device__ __forceinline__ float sigmoidf_(float x) { return 1.f / (1.f + __expf(-x)); }
__device__ __forceinline__ float dswishf_(float x)  { return x * sigmoidf_(x - 1.f); }
__device__ __forceinline__ float clampd_(float x)   { return fminf(fmaxf(x, -1e4f), 1e4f); }
// f32 -> bf16 round-to-nearest-even
__device__ __forceinline__ u16 f2bf_(float x) {
    unsigned u = __float_as_uint(x);
    return (u16)((u + 0x7fffu + ((u >> 16) & 1u)) >> 16);
}

// ---------------------------------------------------------------------------
// bf16 MFMA GEMM: out(N,M) = [res +] act(A(N,K) @ W(M,K)^T + b)
// 128x128 tile, BK=32, 4 waves (2x2 quadrants of 64x64), f32 accum.
// ONE mfma_16x16x32 per (i,j) per K-tile: lane fragment k = (lane>>4)*8..+8,
// the wave's 4 quads jointly cover K=32.  [R4 bug: issuing it twice per tile]
// N, M multiples of 128; K multiple of 32.
// ---------------------------------------------------------------------------
template <int ACT, bool HAS_RES, bool O32, bool O16>
__global__ __launch_bounds__(256) void gemm_mfma(
    const u16* __restrict__ A, const u16* __restrict__ W,
    const float* __restrict__ bias, const float* __restrict__ res,
    float* __restrict__ out32, u16* __restrict__ out16, int N, int K, int M)
{
    __shared__ __align__(16) u16 As[128 * 32];
    __shared__ __align__(16) u16 Bs[128 * 32];
    const int tid  = threadIdx.x;
    const int wv   = tid >> 6;
    const int lane = tid & 63;
    const int wm   = wv >> 1, wn = wv & 1;
    const int m0 = blockIdx.x * 128;
    const int n0 = blockIdx.y * 128;

    const int sc_ = tid & 3;            // k-chunk (8 elems = 16B)
    const int sr_ = tid >> 2;           // staging row 0..63
    const u16* gA = A + (size_t)(n0 + sr_) * K + sc_ * 8;
    const u16* gB = W + (size_t)(m0 + sr_) * K + sc_ * 8;
    const int ls = sr_ * 32 + sc_ * 8;
    const size_t rowK64 = (size_t)64 * K;

    f32x4 acc[4][4];
#pragma unroll
    for (int i = 0; i < 4; ++i)
#pragma unroll
        for (int j = 0; j < 4; ++j) acc[i][j] = (f32x4)0.f;

    const int frow = (lane & 15);       // fragment row (m/n within 16-block)
    const int fk   = (lane >> 4) * 8;   // fragment k offset (quad*8)

    for (int k0 = 0; k0 < K; k0 += 32) {
        const uint4 a0 = *(const uint4*)(gA + k0);
        const uint4 a1 = *(const uint4*)(gA + k0 + rowK64);
        const uint4 b0 = *(const uint4*)(gB + k0);
        const uint4 b1 = *(const uint4*)(gB + k0 + rowK64);
        *(uint4*)&As[ls]        = a0;
        *(uint4*)&As[2048 + ls] = a1;
        *(uint4*)&Bs[ls]        = b0;
        *(uint4*)&Bs[2048 + ls] = b1;
        __syncthreads();
        bf16x8 af[4], bf[4];
#pragma unroll
        for (int i = 0; i < 4; ++i)
            af[i] = *(const bf16x8*)&As[(wm * 64 + i * 16 + frow) * 32 + fk];
#pragma unroll
        for (int j = 0; j < 4; ++j)
            bf[j] = *(const bf16x8*)&Bs[(wn * 64 + j * 16 + frow) * 32 + fk];
#pragma unroll
        for (int i = 0; i < 4; ++i)
#pragma unroll
            for (int j = 0; j < 4; ++j)
                acc[i][j] = __builtin_amdgcn_mfma_f32_16x16x32_bf16(af[i], bf[j], acc[i][j], 0, 0, 0);
        __syncthreads();
    }

    // epilogue: C/D layout col=lane&15, row=(lane>>4)*4+reg  [m89/m91-verified]
    const int quad = lane >> 4;
#pragma unroll
    for (int i = 0; i < 4; ++i) {
        const int row = n0 + wm * 64 + i * 16 + quad * 4;
#pragma unroll
        for (int j = 0; j < 4; ++j) {
            const int col = m0 + wn * 64 + j * 16 + (lane & 15);
            const float bv = bias ? bias[col] : 0.f;
#pragma unroll
            for (int r = 0; r < 4; ++r) {
                float v = acc[i][j][r] + bv;
                if (ACT == 1) v = dswishf_(v);
                if (HAS_RES) v += res[(size_t)(row + r) * M + col];
                v = clampd_(v);
                if (O32) out32[(size_t)(row + r) * M + col] = v;
                if (O16) out16[(size_t)(row + r) * M + col] = f2bf_(v);
            }
        }
    }
}

// ---------------------------------------------------------------------------
// f32 -> bf16 converters
// ---------------------------------------------------------------------------
__device__ __forceinline__ void store_bf4_(u16* out, float4 v) {
    const unsigned lo = (unsigned)f2bf_(v.x) | ((unsigned)f2bf_(v.y) << 16);
    const unsigned hi = (unsigned)f2bf_(v.z) | ((unsigned)f2bf_(v.w) << 16);
    *(uint2*)out = make_uint2(lo, hi);
}

__global__ __launch_bounds__(256) void cvt_k(const float* __restrict__ in, u16* __restrict__ out)
{
    const int i4 = (blockIdx.x * 256 + threadIdx.x) * 4;
    store_bf4_(out + i4, *(const float4*)(in + i4));
}

// all 9 weight matrices, concatenated dst; region-dispatched src
struct WPtrs { const float* p[9]; };
__global__ __launch_bounds__(256) void cvt_w_k(WPtrs wp, u16* __restrict__ out)
{
    static const int off[10] = {0, 1048576, 2097152, 3145728, 4194304,
                                4980736, 5242880, 5505024, 6029312, 6291456};
    const int e = (blockIdx.x * 256 + threadIdx.x) * 4;
    int r = 0;
#pragma unroll
    for (int k = 1; k < 9; ++k) r += (e >= off[k]);
    store_bf4_(out + e, *(const float4*)(wp.p[r] + (e - off[r])));
}

// pos_emb (1023x512) -> bf16 padded to 1024 rows (row 1023 = 0)
__global__ __launch_bounds__(256) void cvt_pos_k(const float* __restrict__ in, u16* __restrict__ out)
{
    const int e = (blockIdx.x * 256 + threadIdx.x) * 4;
    float4 v = make_float4(0.f, 0.f, 0.f, 0.f);
    if (e < 1023 * 512) v = *(const float4*)(in + e);
    store_bf4_(out + e, v);
}

// ---------------------------------------------------------------------------
// Attention (f32, R1-proven; softmax clamps inputs; PV writes bf16)
// ---------------------------------------------------------------------------
__global__ __launch_bounds__(256) void attn_scores(
    const float* __restrict__ qkv, const float* __restrict__ pmat,
    const float* __restrict__ ub, const float* __restrict__ vb,
    float* __restrict__ scores, int b0)
{
    __shared__ float qu[32][65], qv[32][65], ks[64][65], ps[96][65];
    const int tid = threadIdx.x;
    const int s0 = blockIdx.x * 64;
    const int t0 = blockIdx.y * 32;
    const int bhl = blockIdx.z;
    const int bl = bhl >> 3, h = bhl & 7;
    const int b = b0 + bl;
    const int jbase = s0 - t0 + 480;

    for (int e = tid; e < 32 * 64; e += 256) {
        const int tt = e >> 6, d = e & 63;
        const float q = qkv[((size_t)(t0 + tt) * B_SZ + b) * 1536 + h * 64 + d] * 0.125f;
        qu[tt][d] = q + ub[h * 64 + d];
        qv[tt][d] = q + vb[h * 64 + d];
    }
    for (int e = tid; e < 64 * 64; e += 256) {
        const int ss = e >> 6, d = e & 63;
        ks[ss][d] = qkv[((size_t)(s0 + ss) * B_SZ + b) * 1536 + 512 + h * 64 + d];
    }
    for (int e = tid; e < 96 * 64; e += 256) {
        const int jl = e >> 6, d = e & 63;
        const int j = jbase + jl;
        ps[jl][d] = (j < 1023) ? pmat[(size_t)j * 512 + h * 64 + d] : 0.f;
    }
    __syncthreads();

    const int tt0 = (tid >> 4) << 1;
    const int ss0 = (tid & 15) << 2;
    float acc0[4] = {}, acc1[4] = {};
#pragma unroll 4
    for (int d = 0; d < 64; ++d) {
        const float a0u = qu[tt0][d], a1u = qu[tt0 + 1][d];
        const float a0v = qv[tt0][d], a1v = qv[tt0 + 1][d];
#pragma unroll
        for (int j = 0; j < 4; ++j) {
            const float bk = ks[ss0 + j][d];
            const int r = 31 - tt0 + ss0 + j;
            acc0[j] += a0u * bk + a0v * ps[r][d];
            acc1[j] += a1u * bk + a1v * ps[r - 1][d];
        }
    }
    const size_t base = ((size_t)bhl * 512 + t0 + tt0) * 512 + s0 + ss0;
#pragma unroll
    for (int j = 0; j < 4; ++j) {
        scores[base + j] = acc0[j];
        scores[base + 512 + j] = acc1[j];
    }
}

__global__ __launch_bounds__(256) void softmax_rows(float* __restrict__ s)
{
    const int row = blockIdx.x * 4 + (threadIdx.x >> 6);
    const int lane = threadIdx.x & 63;
    float* r = s + (size_t)row * 512;
    float v[8];
    float mx = -1e30f;
#pragma unroll
    for (int j = 0; j < 8; ++j) { v[j] = clampd_(r[lane + (j << 6)]); mx = fmaxf(mx, v[j]); }
#pragma unroll
    for (int o = 32; o > 0; o >>= 1) mx = fmaxf(mx, __shfl_xor(mx, o, 64));
    float sum = 0.f;
#pragma unroll
    for (int j = 0; j < 8; ++j) { v[j] = __expf(v[j] - mx); sum += v[j]; }
#pragma unroll
    for (int o = 32; o > 0; o >>= 1) sum += __shfl_xor(sum, o, 64);
    const float inv = 1.f / sum;
#pragma unroll
    for (int j = 0; j < 8; ++j) r[lane + (j << 6)] = v[j] * inv;
}

// ao_bf16[t, b, h*64+d] = sum_s attn[bhl,t,s] * v[s,b,h,d]
__global__ __launch_bounds__(256) void attn_pv(
    const float* __restrict__ scores, const float* __restrict__ qkv,
    u16* __restrict__ aob, int b0)
{
    __shared__ __align__(16) float At[16][64];
    __shared__ __align__(16) float Vs[16][64];
    const int tid = threadIdx.x;
    const int t0 = blockIdx.x * 64;
    const int bhl = blockIdx.y;
    const int bl = bhl >> 3, h = bhl & 7;
    const int b = b0 + bl;
    const int tx = tid & 15, ty = tid >> 4;
    const int ln = tid >> 2, lk = (tid & 3) << 2;
    const int vs_s = tid >> 4, vs_d = (tid & 15) << 2;
    float acc[4][4] = {};
    const float* arow = scores + ((size_t)bhl * 512 + t0 + ln) * 512 + lk;

    for (int k0 = 0; k0 < 512; k0 += 16) {
        const float4 av = *(const float4*)(arow + k0);
        At[lk + 0][ln] = av.x; At[lk + 1][ln] = av.y;
        At[lk + 2][ln] = av.z; At[lk + 3][ln] = av.w;
        const float4 vv = *(const float4*)(qkv + ((size_t)(k0 + vs_s) * B_SZ + b) * 1536 + 1024 + h * 64 + vs_d);
        *(float4*)&Vs[vs_s][vs_d] = vv;
        __syncthreads();
#pragma unroll
        for (int kk = 0; kk < 16; ++kk) {
            const float4 a = *(const float4*)&At[kk][ty << 2];
            const float4 bvv = *(const float4*)&Vs[kk][tx << 2];
            const float aa[4] = {a.x, a.y, a.z, a.w};
            const float bb[4] = {bvv.x, bvv.y, bvv.z, bvv.w};
#pragma unroll
            for (int i = 0; i < 4; ++i)
#pragma unroll
                for (int j = 0; j < 4; ++j) acc[i][j] += aa[i] * bb[j];
        }
        __syncthreads();
    }
#pragma unroll
    for (int i = 0; i < 4; ++i) {
        const int t = t0 + (ty << 2) + i;
        u16* orow = aob + ((size_t)t * B_SZ + b) * 512 + h * 64 + (tx << 2);
#pragma unroll
        for (int j = 0; j < 4; ++j) orow[j] = f2bf_(acc[i][j]);
    }
}

// ---------------------------------------------------------------------------
// Conv-module pieces
// ---------------------------------------------------------------------------
__global__ __launch_bounds__(256) void glu_k(const float* __restrict__ in, float* __restrict__ out)
{
    const int idx = blockIdx.x * 256 + threadIdx.x;
    const int n = idx >> 9, c = idx & 511;
    const float a = in[(size_t)n * 1024 + c];
    const float g = in[(size_t)n * 1024 + 512 + c];
    out[idx] = a * sigmoidf_(g);
}

// causal depthwise conv (K=31, left-pad 30) + DoubleSwish -> bf16
__global__ __launch_bounds__(256) void dwconv_k(
    const float* __restrict__ g, const float* __restrict__ w,
    const float* __restrict__ bb, u16* __restrict__ out)
{
    const int idx = blockIdx.x * 256 + threadIdx.x;
    const int c = idx & 511;
    const int tb = idx >> 9;
    const int b = tb & 15, t = tb >> 4;
    float acc = bb[c];
#pragma unroll
    for (int j = 0; j < 31; ++j) {
        const int tt = t - 30 + j;
        if (tt >= 0) acc += g[((size_t)tt * B_SZ + b) * 512 + c] * w[c * 31 + j];
    }
    out[idx] = f2bf_(dswishf_(acc));
}

__global__ __launch_bounds__(256) void norm_k(float* __restrict__ x)
{
    const int row = blockIdx.x * 4 + (threadIdx.x >> 6);
    const int lane = threadIdx.x & 63;
    float* r = x + (size_t)row * 512;
    float v[8];
    float ss = 0.f;
#pragma unroll
    for (int j = 0; j < 8; ++j) { v[j] = r[lane + (j << 6)]; ss += v[j] * v[j]; }
#pragma unroll
    for (int o = 32; o > 0; o >>= 1) ss += __shfl_xor(ss, o, 64);
    const float scale = rsqrtf(ss * (1.f / 512.f) + EPS_BN);
#pragma unroll
    for (int j = 0; j < 8; ++j) r[lane + (j << 6)] = v[j] * scale;
}

// ---------------------------------------------------------------------------
extern "C" void kernel_launch(void* const* d_in, const int* in_sizes, int n_in,
                              void* d_out, int out_size, void* d_ws, size_t ws_size,
                              hipStream_t stream)
{
    const float* src   = (const float*)d_in[0];
    const float* pos   = (const float*)d_in[1];
    const float* fm_w1 = (const float*)d_in[2];
    const float* fm_b1 = (const float*)d_in[3];
    const float* fm_w2 = (const float*)d_in[4];
    const float* fm_b2 = (const float*)d_in[5];
    const float* f_w1  = (const float*)d_in[6];
    const float* f_b1  = (const float*)d_in[7];
    const float* f_w2  = (const float*)d_in[8];
    const float* f_b2  = (const float*)d_in[9];
    const float* ipw   = (const float*)d_in[10];
    const float* ipb   = (const float*)d_in[11];
    const float* opw   = (const float*)d_in[12];
    const float* opb   = (const float*)d_in[13];
    const float* lpw   = (const float*)d_in[14];
    const float* pbu   = (const float*)d_in[15];
    const float* pbv   = (const float*)d_in[16];
    const float* cpw1  = (const float*)d_in[17];
    const float* cpb1  = (const float*)d_in[18];
    const float* cdw   = (const float*)d_in[19];
    const float* cdb   = (const float*)d_in[20];
    const float* cpw2  = (const float*)d_in[21];
    const float* cpb2  = (const float*)d_in[22];

    float* x = (float*)d_out;              // running activation (8192 x 512) f32

    // ---- workspace layout (~158.4 MB) ----
    char* base = (char*)d_ws;
    u16*   wb    = (u16*)base;   base += 6291456ull * 2;   // 9 weights bf16
    u16*   src_b = (u16*)base;   base += 4194304ull * 2;
    u16*   pos_b = (u16*)base;   base += 524288ull * 2;    // 1024x512 padded
    u16*   xb    = (u16*)base;   base += 4194304ull * 2;
    u16*   hb    = (u16*)base;   base += 16777216ull * 2;  // 8192x2048
    u16*   aob   = (u16*)base;   base += 4194304ull * 2;
    float* qkvb  = (float*)base; base += 12582912ull * 4;  // union: glu_out
    float* pm    = (float*)base; base += 524288ull * 4;
    float* sc    = (float*)base; base += 8388608ull * 4;   // union: pw1_out
    float* glu_o = qkvb;                                   // 8192x512 f32 (after attn)
    float* pw1_o = sc;                                     // 8192x1024 f32 (after attn)

    u16* fm_w1b = wb;
    u16* fm_w2b = wb + 1048576;
    u16* f_w1b  = wb + 2097152;
    u16* f_w2b  = wb + 3145728;
    u16* ipwb   = wb + 4194304;
    u16* opwb   = wb + 4980736;
    u16* lpwb   = wb + 5242880;
    u16* cpw1b  = wb + 5505024;
    u16* cpw2b  = wb + 6029312;

    const dim3 blk(256);

    // 0) f32 -> bf16 conversions
    WPtrs wp = {{fm_w1, fm_w2, f_w1, f_w2, ipw, opw, lpw, cpw1, cpw2}};
    cvt_w_k<<<dim3(6291456 / 1024), blk, 0, stream>>>(wp, wb);
    cvt_k<<<dim3(4194304 / 1024), blk, 0, stream>>>(src, src_b);
    cvt_pos_k<<<dim3(524288 / 1024), blk, 0, stream>>>(pos, pos_b);

    // 1) macaron FFN: x = src + W2 @ dswish(W1 @ src)
    gemm_mfma<1, false, false, true><<<dim3(16, 64), blk, 0, stream>>>(
        src_b, fm_w1b, fm_b1, nullptr, nullptr, hb, NROWS, 512, DFF_);
    gemm_mfma<0, true, true, true><<<dim3(4, 64), blk, 0, stream>>>(
        hb, fm_w2b, fm_b2, src, x, xb, NROWS, DFF_, 512);

    // 2) qkv and positional projections (f32 outputs for f32 attention)
    gemm_mfma<0, false, true, false><<<dim3(12, 64), blk, 0, stream>>>(
        xb, ipwb, ipb, nullptr, qkvb, nullptr, NROWS, 512, 1536);
    gemm_mfma<0, false, true, false><<<dim3(4, 8), blk, 0, stream>>>(
        pos_b, lpwb, nullptr, nullptr, pm, nullptr, 1024, 512, 512);

    // 3) rel-pos attention, chunked over batch
    for (int bc = 0; bc < B_SZ / BCHUNK; ++bc) {
        attn_scores<<<dim3(8, 16, BCHUNK * NH), blk, 0, stream>>>(qkvb, pm, pbu, pbv, sc, bc * BCHUNK);
        softmax_rows<<<dim3(BCHUNK * NH * 512 / 4), blk, 0, stream>>>(sc);
        attn_pv<<<dim3(8, BCHUNK * NH), blk, 0, stream>>>(sc, qkvb, aob, bc * BCHUNK);
    }

    // 4) out projection (residual into x)
    gemm_mfma<0, true, true, true><<<dim3(4, 64), blk, 0, stream>>>(
        aob, opwb, opb, x, x, xb, NROWS, 512, 512);

    // 5) conv module: pw1 -> GLU -> causal dwconv(+dswish, ->bf16) -> pw2 (residual)
    gemm_mfma<0, false, true, false><<<dim3(8, 64), blk, 0, stream>>>(
        xb, cpw1b, cpb1, nullptr, pw1_o, nullptr, NROWS, 512, 1024);
    glu_k<<<dim3(NROWS * 512 / 256), blk, 0, stream>>>(pw1_o, glu_o);
    dwconv_k<<<dim3(NROWS * 512 / 256), blk, 0, stream>>>(glu_o, cdw, cdb, hb);
    gemm_mfma<0, true, true, true><<<dim3(4, 64), blk, 0, stream>>>(
        hb, cpw2b, cpb2, x, x, xb, NROWS, 512, 512);

    // 6) second FFN
    gemm_mfma<1, false, false, true><<<dim3(16, 64), blk, 0, stream>>>(
        xb, f_w1b, f_b1, nullptr, nullptr, hb, NROWS, 512, DFF_);
    gemm_mfma<0, true, true, false><<<dim3(4, 64), blk, 0, stream>>>(
        hb, f_w2b, f_b2, x, x, nullptr, NROWS, DFF_, 512);

    // 7) BasicNorm
    norm_k<<<dim3(NROWS / 4), blk, 0, stream>>>(x);
}

// Round 6
// 664.160 us; speedup vs baseline: 3.6325x; 1.9106x over previous
//
#include <hip/hip_runtime.h>
#include <math.h>

// Problem constants (ConformerEncoderLayer, T=512 B=16 C=512 H=8 d=64 DFF=2048 K=31)
#define T_SEQ 512
#define B_SZ  16
#define C_DIM 512
#define NH    8
#define HD    64
#define DFF_  2048
#define NROWS (T_SEQ * B_SZ)   // 8192 rows of (t*B+b)
#define BCHUNK 4               // attention batches per chunk (32 bh per chunk)
#define EPS_BN 1.2840254166877414f  // exp(0.25)

typedef unsigned short u16;
typedef __attribute__((ext_vector_type(8))) short bf16x8;
typedef __attribute__((ext_vector_type(4))) float f32x4;

__device__ __forceinline__ float sigmoidf_(float x) { return 1.f / (1.f + __expf(-x)); }
__device__ __forceinline__ float dswishf_(float x)  { return x * sigmoidf_(x - 1.f); }
__device__ __forceinline__ float clampd_(float x)   { return fminf(fmaxf(x, -1e4f), 1e4f); }
__device__ __forceinline__ u16 f2bf_(float x) {
    unsigned u = __float_as_uint(x);
    return (u16)((u + 0x7fffu + ((u >> 16) & 1u)) >> 16);
}
__device__ __forceinline__ float bf2f_(u16 u) {
    return __uint_as_float(((unsigned)u) << 16);
}

// ---------------------------------------------------------------------------
// bf16 MFMA GEMM (R5-proven): out(N,M) = [res +] act(A(N,K) @ W(M,K)^T + b)
// 128x128 tile, BK=32, 4 waves (2x2 of 64x64), ONE mfma_16x16x32 per (i,j)
// per K-tile (quads jointly cover K=32). N,M mult of 128; K mult of 32.
// ---------------------------------------------------------------------------
template <int ACT, bool HAS_RES, bool O32, bool O16>
__global__ __launch_bounds__(256) void gemm_mfma(
    const u16* __restrict__ A, const u16* __restrict__ W,
    const float* __restrict__ bias, const float* __restrict__ res,
    float* __restrict__ out32, u16* __restrict__ out16, int N, int K, int M)
{
    __shared__ __align__(16) u16 As[128 * 32];
    __shared__ __align__(16) u16 Bs[128 * 32];
    const int tid  = threadIdx.x;
    const int wv   = tid >> 6;
    const int lane = tid & 63;
    const int wm   = wv >> 1, wn = wv & 1;
    const int m0 = blockIdx.x * 128;
    const int n0 = blockIdx.y * 128;

    const int sc_ = tid & 3;
    const int sr_ = tid >> 2;
    const u16* gA = A + (size_t)(n0 + sr_) * K + sc_ * 8;
    const u16* gB = W + (size_t)(m0 + sr_) * K + sc_ * 8;
    const int ls = sr_ * 32 + sc_ * 8;
    const size_t rowK64 = (size_t)64 * K;

    f32x4 acc[4][4];
#pragma unroll
    for (int i = 0; i < 4; ++i)
#pragma unroll
        for (int j = 0; j < 4; ++j) acc[i][j] = (f32x4)0.f;

    const int frow = (lane & 15);
    const int fk   = (lane >> 4) * 8;

    for (int k0 = 0; k0 < K; k0 += 32) {
        const uint4 a0 = *(const uint4*)(gA + k0);
        const uint4 a1 = *(const uint4*)(gA + k0 + rowK64);
        const uint4 b0 = *(const uint4*)(gB + k0);
        const uint4 b1 = *(const uint4*)(gB + k0 + rowK64);
        *(uint4*)&As[ls]        = a0;
        *(uint4*)&As[2048 + ls] = a1;
        *(uint4*)&Bs[ls]        = b0;
        *(uint4*)&Bs[2048 + ls] = b1;
        __syncthreads();
        bf16x8 af[4], bf[4];
#pragma unroll
        for (int i = 0; i < 4; ++i)
            af[i] = *(const bf16x8*)&As[(wm * 64 + i * 16 + frow) * 32 + fk];
#pragma unroll
        for (int j = 0; j < 4; ++j)
            bf[j] = *(const bf16x8*)&Bs[(wn * 64 + j * 16 + frow) * 32 + fk];
#pragma unroll
        for (int i = 0; i < 4; ++i)
#pragma unroll
            for (int j = 0; j < 4; ++j)
                acc[i][j] = __builtin_amdgcn_mfma_f32_16x16x32_bf16(af[i], bf[j], acc[i][j], 0, 0, 0);
        __syncthreads();
    }

    const int quad = lane >> 4;
#pragma unroll
    for (int i = 0; i < 4; ++i) {
        const int row = n0 + wm * 64 + i * 16 + quad * 4;
#pragma unroll
        for (int j = 0; j < 4; ++j) {
            const int col = m0 + wn * 64 + j * 16 + (lane & 15);
            const float bv = bias ? bias[col] : 0.f;
#pragma unroll
            for (int r = 0; r < 4; ++r) {
                float v = acc[i][j][r] + bv;
                if (ACT == 1) v = dswishf_(v);
                if (HAS_RES) v += res[(size_t)(row + r) * M + col];
                v = clampd_(v);
                if (O32) out32[(size_t)(row + r) * M + col] = v;
                if (O16) out16[(size_t)(row + r) * M + col] = f2bf_(v);
            }
        }
    }
}

// ---------------------------------------------------------------------------
// f32 -> bf16 converters
// ---------------------------------------------------------------------------
__device__ __forceinline__ void store_bf4_(u16* out, float4 v) {
    const unsigned lo = (unsigned)f2bf_(v.x) | ((unsigned)f2bf_(v.y) << 16);
    const unsigned hi = (unsigned)f2bf_(v.z) | ((unsigned)f2bf_(v.w) << 16);
    *(uint2*)out = make_uint2(lo, hi);
}

__global__ __launch_bounds__(256) void cvt_k(const float* __restrict__ in, u16* __restrict__ out)
{
    const int i4 = (blockIdx.x * 256 + threadIdx.x) * 4;
    store_bf4_(out + i4, *(const float4*)(in + i4));
}

struct WPtrs { const float* p[9]; };
__global__ __launch_bounds__(256) void cvt_w_k(WPtrs wp, u16* __restrict__ out)
{
    static const int off[10] = {0, 1048576, 2097152, 3145728, 4194304,
                                4980736, 5242880, 5505024, 6029312, 6291456};
    const int e = (blockIdx.x * 256 + threadIdx.x) * 4;
    int r = 0;
#pragma unroll
    for (int k = 1; k < 9; ++k) r += (e >= off[k]);
    store_bf4_(out + e, *(const float4*)(wp.p[r] + (e - off[r])));
}

// pos_emb (1023x512) -> bf16 padded to 1024 rows (row 1023 = 0)
__global__ __launch_bounds__(256) void cvt_pos_k(const float* __restrict__ in, u16* __restrict__ out)
{
    const int e = (blockIdx.x * 256 + threadIdx.x) * 4;
    float4 v = make_float4(0.f, 0.f, 0.f, 0.f);
    if (e < 1023 * 512) v = *(const float4*)(in + e);
    store_bf4_(out + e, v);
}

// ---------------------------------------------------------------------------
// Attention prep: from f32 qkv (t*16+b, 1536) build bf16 per-(b,h) buffers:
//   qu_b/qv_b/k_b/v_b [gbh][t][64]  (q scaled 0.125, u/v bias added to q)
// ---------------------------------------------------------------------------
__global__ __launch_bounds__(256) void repack_qkv(
    const float* __restrict__ qkv, const float* __restrict__ ub, const float* __restrict__ vb,
    u16* __restrict__ qu_b, u16* __restrict__ qv_b, u16* __restrict__ k_b, u16* __restrict__ v_b)
{
    const int idx = blockIdx.x * 256 + threadIdx.x;   // [0, 128*512*64)
    const int d = idx & 63;
    const int t = (idx >> 6) & 511;
    const int gbh = idx >> 15;
    const int b = gbh >> 3, h = gbh & 7;
    const size_t src = ((size_t)t * B_SZ + b) * 1536 + h * 64 + d;
    const float q = qkv[src] * 0.125f;
    qu_b[idx] = f2bf_(q + ub[h * 64 + d]);
    qv_b[idx] = f2bf_(q + vb[h * 64 + d]);
    k_b[idx]  = f2bf_(qkv[src + 512]);
    v_b[idx]  = f2bf_(qkv[src + 1024]);
}

// pm (1024x512 f32, row1023=0) -> p_b[h][j][64] bf16
__global__ __launch_bounds__(256) void repack_p(const float* __restrict__ pm, u16* __restrict__ p_b)
{
    const int idx = blockIdx.x * 256 + threadIdx.x;   // [0, 8*1024*64)
    const int d = idx & 63;
    const int j = (idx >> 6) & 1023;
    const int h = idx >> 16;
    p_b[idx] = f2bf_(pm[(size_t)j * 512 + h * 64 + d]);
}

// ---------------------------------------------------------------------------
// C2[bhl][t][j] = qv[t,:] . p[h][j,:]  (K=64 MFMA gemm, bf16 out, 1024 cols)
// grid (j-tiles=8, t-tiles=4, bhl=32)
// ---------------------------------------------------------------------------
__global__ __launch_bounds__(256) void c2_mfma(
    const u16* __restrict__ qv_b, const u16* __restrict__ p_b,
    u16* __restrict__ c2b, int b0)
{
    __shared__ __align__(16) u16 As[128 * 32];
    __shared__ __align__(16) u16 Bs[128 * 32];
    const int tid  = threadIdx.x;
    const int wv   = tid >> 6;
    const int lane = tid & 63;
    const int wm   = wv >> 1, wn = wv & 1;
    const int m0 = blockIdx.x * 128;     // j
    const int n0 = blockIdx.y * 128;     // t
    const int bhl = blockIdx.z;
    const int gbh = b0 * 8 + bhl;
    const int h = bhl & 7;

    const int K = 64;
    const u16* A = qv_b + (size_t)gbh * 512 * 64;
    const u16* W = p_b + (size_t)h * 1024 * 64;

    const int sc_ = tid & 3;
    const int sr_ = tid >> 2;
    const u16* gA = A + (size_t)(n0 + sr_) * K + sc_ * 8;
    const u16* gB = W + (size_t)(m0 + sr_) * K + sc_ * 8;
    const int ls = sr_ * 32 + sc_ * 8;
    const size_t rowK64 = (size_t)64 * K;

    f32x4 acc[4][4];
#pragma unroll
    for (int i = 0; i < 4; ++i)
#pragma unroll
        for (int j = 0; j < 4; ++j) acc[i][j] = (f32x4)0.f;

    const int frow = (lane & 15);
    const int fk   = (lane >> 4) * 8;

    for (int k0 = 0; k0 < K; k0 += 32) {
        const uint4 a0 = *(const uint4*)(gA + k0);
        const uint4 a1 = *(const uint4*)(gA + k0 + rowK64);
        const uint4 b0v = *(const uint4*)(gB + k0);
        const uint4 b1v = *(const uint4*)(gB + k0 + rowK64);
        *(uint4*)&As[ls]        = a0;
        *(uint4*)&As[2048 + ls] = a1;
        *(uint4*)&Bs[ls]        = b0v;
        *(uint4*)&Bs[2048 + ls] = b1v;
        __syncthreads();
        bf16x8 af[4], bf[4];
#pragma unroll
        for (int i = 0; i < 4; ++i)
            af[i] = *(const bf16x8*)&As[(wm * 64 + i * 16 + frow) * 32 + fk];
#pragma unroll
        for (int j = 0; j < 4; ++j)
            bf[j] = *(const bf16x8*)&Bs[(wn * 64 + j * 16 + frow) * 32 + fk];
#pragma unroll
        for (int i = 0; i < 4; ++i)
#pragma unroll
            for (int j = 0; j < 4; ++j)
                acc[i][j] = __builtin_amdgcn_mfma_f32_16x16x32_bf16(af[i], bf[j], acc[i][j], 0, 0, 0);
        __syncthreads();
    }

    const int quad = lane >> 4;
    u16* outb = c2b + (size_t)bhl * 512 * 1024;
#pragma unroll
    for (int i = 0; i < 4; ++i) {
        const int row = n0 + wm * 64 + i * 16 + quad * 4;
#pragma unroll
        for (int j = 0; j < 4; ++j) {
            const int col = m0 + wn * 64 + j * 16 + (lane & 15);
#pragma unroll
            for (int r = 0; r < 4; ++r)
                outb[(size_t)(row + r) * 1024 + col] = f2bf_(acc[i][j][r]);
        }
    }
}

// ---------------------------------------------------------------------------
// scores[bhl][t][s] = qu[t,:].k[s,:] + C2[bhl][t][511-t+s]   (f32 out, clamped)
// grid (s-tiles=4, t-tiles=4, bhl=32)
// ---------------------------------------------------------------------------
__global__ __launch_bounds__(256) void scores_c1(
    const u16* __restrict__ qu_b, const u16* __restrict__ k_b,
    const u16* __restrict__ c2b, float* __restrict__ sc, int b0)
{
    __shared__ __align__(16) u16 As[128 * 32];
    __shared__ __align__(16) u16 Bs[128 * 32];
    const int tid  = threadIdx.x;
    const int wv   = tid >> 6;
    const int lane = tid & 63;
    const int wm   = wv >> 1, wn = wv & 1;
    const int m0 = blockIdx.x * 128;     // s
    const int n0 = blockIdx.y * 128;     // t
    const int bhl = blockIdx.z;
    const int gbh = b0 * 8 + bhl;

    const int K = 64;
    const u16* A = qu_b + (size_t)gbh * 512 * 64;
    const u16* W = k_b + (size_t)gbh * 512 * 64;

    const int sc_ = tid & 3;
    const int sr_ = tid >> 2;
    const u16* gA = A + (size_t)(n0 + sr_) * K + sc_ * 8;
    const u16* gB = W + (size_t)(m0 + sr_) * K + sc_ * 8;
    const int ls = sr_ * 32 + sc_ * 8;
    const size_t rowK64 = (size_t)64 * K;

    f32x4 acc[4][4];
#pragma unroll
    for (int i = 0; i < 4; ++i)
#pragma unroll
        for (int j = 0; j < 4; ++j) acc[i][j] = (f32x4)0.f;

    const int frow = (lane & 15);
    const int fk   = (lane >> 4) * 8;

    for (int k0 = 0; k0 < K; k0 += 32) {
        const uint4 a0 = *(const uint4*)(gA + k0);
        const uint4 a1 = *(const uint4*)(gA + k0 + rowK64);
        const uint4 b0v = *(const uint4*)(gB + k0);
        const uint4 b1v = *(const uint4*)(gB + k0 + rowK64);
        *(uint4*)&As[ls]        = a0;
        *(uint4*)&As[2048 + ls] = a1;
        *(uint4*)&Bs[ls]        = b0v;
        *(uint4*)&Bs[2048 + ls] = b1v;
        __syncthreads();
        bf16x8 af[4], bf[4];
#pragma unroll
        for (int i = 0; i < 4; ++i)
            af[i] = *(const bf16x8*)&As[(wm * 64 + i * 16 + frow) * 32 + fk];
#pragma unroll
        for (int j = 0; j < 4; ++j)
            bf[j] = *(const bf16x8*)&Bs[(wn * 64 + j * 16 + frow) * 32 + fk];
#pragma unroll
        for (int i = 0; i < 4; ++i)
#pragma unroll
            for (int j = 0; j < 4; ++j)
                acc[i][j] = __builtin_amdgcn_mfma_f32_16x16x32_bf16(af[i], bf[j], acc[i][j], 0, 0, 0);
        __syncthreads();
    }

    const int quad = lane >> 4;
    const u16* c2base = c2b + (size_t)bhl * 512 * 1024;
    float* scb = sc + (size_t)bhl * 512 * 512;
#pragma unroll
    for (int i = 0; i < 4; ++i) {
        const int row = n0 + wm * 64 + i * 16 + quad * 4;
#pragma unroll
        for (int j = 0; j < 4; ++j) {
            const int col = m0 + wn * 64 + j * 16 + (lane & 15);
#pragma unroll
            for (int r = 0; r < 4; ++r) {
                const int t = row + r;
                const float bd = bf2f_(c2base[(size_t)t * 1024 + (511 - t + col)]);
                scb[(size_t)t * 512 + col] = clampd_(acc[i][j][r] + bd);
            }
        }
    }
}

// softmax over 512-long rows: f32 scores in -> bf16 probs out
__global__ __launch_bounds__(256) void softmax_rows(
    const float* __restrict__ s, u16* __restrict__ p)
{
    const int row = blockIdx.x * 4 + (threadIdx.x >> 6);
    const int lane = threadIdx.x & 63;
    const float* r = s + (size_t)row * 512;
    u16* o = p + (size_t)row * 512;
    float v[8];
    float mx = -1e30f;
#pragma unroll
    for (int j = 0; j < 8; ++j) { v[j] = r[lane + (j << 6)]; mx = fmaxf(mx, v[j]); }
#pragma unroll
    for (int off = 32; off > 0; off >>= 1) mx = fmaxf(mx, __shfl_xor(mx, off, 64));
    float sum = 0.f;
#pragma unroll
    for (int j = 0; j < 8; ++j) { v[j] = __expf(v[j] - mx); sum += v[j]; }
#pragma unroll
    for (int off = 32; off > 0; off >>= 1) sum += __shfl_xor(sum, off, 64);
    const float inv = 1.f / sum;
#pragma unroll
    for (int j = 0; j < 8; ++j) o[lane + (j << 6)] = f2bf_(v[j] * inv);
}

// ---------------------------------------------------------------------------
// PV: ao[(t*16+b)*512 + h*64+d] = sum_s probs[bhl][t][s] * v[gbh][s][d]
// tile 128(t) x 64(d), K=512 over s in steps of 32; V transposed through LDS.
// grid (t-tiles=4, bhl=32)
// ---------------------------------------------------------------------------
__global__ __launch_bounds__(256) void pv_mfma(
    const u16* __restrict__ probs, const u16* __restrict__ v_b,
    u16* __restrict__ aob, int b0)
{
    __shared__ __align__(16) u16 Ps[128 * 32];
    __shared__ __align__(16) u16 Vt[64 * 32];
    const int tid  = threadIdx.x;
    const int wv   = tid >> 6;
    const int lane = tid & 63;
    const int t0 = blockIdx.x * 128;
    const int bhl = blockIdx.y;
    const int gbh = b0 * 8 + bhl;
    const int b = gbh >> 3, h = gbh & 7;

    const u16* prow = probs + (size_t)bhl * 512 * 512;
    const u16* vrow = v_b + (size_t)gbh * 512 * 64;

    f32x4 acc[2][4];
#pragma unroll
    for (int i = 0; i < 2; ++i)
#pragma unroll
        for (int j = 0; j < 4; ++j) acc[i][j] = (f32x4)0.f;

    const int frow = (lane & 15);
    const int fk   = (lane >> 4) * 8;
    // probs staging: 512 uint4 per step -> 2 per thread
    const int pl0 = tid * 2;
    // v staging: 256 uint4 -> 1 per thread, transposed into Vt
    const int vss = tid >> 3, vdd = tid & 7;

    for (int s0 = 0; s0 < 512; s0 += 32) {
#pragma unroll
        for (int q = 0; q < 2; ++q) {
            const int lin = pl0 + q;
            const int tt = lin >> 2, ch = lin & 3;
            *(uint4*)&Ps[tt * 32 + ch * 8] =
                *(const uint4*)(prow + (size_t)(t0 + tt) * 512 + s0 + ch * 8);
        }
        uint4 vv = *(const uint4*)(vrow + (size_t)(s0 + vss) * 64 + vdd * 8);
        const u16* vu = (const u16*)&vv;
#pragma unroll
        for (int q = 0; q < 8; ++q)
            Vt[(vdd * 8 + q) * 32 + vss] = vu[q];
        __syncthreads();
        bf16x8 af[2], bf[4];
#pragma unroll
        for (int i = 0; i < 2; ++i)
            af[i] = *(const bf16x8*)&Ps[(wv * 32 + i * 16 + frow) * 32 + fk];
#pragma unroll
        for (int j = 0; j < 4; ++j)
            bf[j] = *(const bf16x8*)&Vt[(j * 16 + frow) * 32 + fk];
#pragma unroll
        for (int i = 0; i < 2; ++i)
#pragma unroll
            for (int j = 0; j < 4; ++j)
                acc[i][j] = __builtin_amdgcn_mfma_f32_16x16x32_bf16(af[i], bf[j], acc[i][j], 0, 0, 0);
        __syncthreads();
    }

    const int quad = lane >> 4;
#pragma unroll
    for (int i = 0; i < 2; ++i) {
        const int trow = t0 + wv * 32 + i * 16 + quad * 4;
#pragma unroll
        for (int j = 0; j < 4; ++j) {
            const int d = j * 16 + (lane & 15);
#pragma unroll
            for (int r = 0; r < 4; ++r)
                aob[((size_t)(trow + r) * B_SZ + b) * 512 + h * 64 + d] = f2bf_(acc[i][j][r]);
        }
    }
}

// ---------------------------------------------------------------------------
// Conv-module pieces
// ---------------------------------------------------------------------------
__global__ __launch_bounds__(256) void glu_k(const float* __restrict__ in, float* __restrict__ out)
{
    const int idx = blockIdx.x * 256 + threadIdx.x;
    const int n = idx >> 9, c = idx & 511;
    const float a = in[(size_t)n * 1024 + c];
    const float g = in[(size_t)n * 1024 + 512 + c];
    out[idx] = a * sigmoidf_(g);
}

// dw weight transpose: w[c][j] (512x31) -> wT[j][c] (31x512)
__global__ __launch_bounds__(256) void dwt_k(const float* __restrict__ w, float* __restrict__ wT)
{
    const int idx = blockIdx.x * 256 + threadIdx.x;
    if (idx >= 31 * 512) return;
    const int j = idx >> 9, c = idx & 511;
    wT[idx] = w[c * 31 + j];
}

// causal depthwise conv (K=31, pad 30) + DoubleSwish -> bf16.
// 8 t-outputs per thread, sliding register window, coalesced wT loads.
__global__ __launch_bounds__(256) void dwconv_k(
    const float* __restrict__ g, const float* __restrict__ wT,
    const float* __restrict__ bb, u16* __restrict__ out)
{
    const int idx = blockIdx.x * 256 + threadIdx.x;   // [0, 64*16*512)
    const int c = idx & 511;
    const int b = (idx >> 9) & 15;
    const int t0 = (idx >> 13) * 8;
    float wr[31];
#pragma unroll
    for (int j = 0; j < 31; ++j) wr[j] = wT[j * 512 + c];
    float win[38];
#pragma unroll
    for (int jj = 0; jj < 38; ++jj) {
        const int tt = t0 - 30 + jj;
        win[jj] = (tt >= 0) ? g[((size_t)tt * B_SZ + b) * 512 + c] : 0.f;
    }
    const float bias = bb[c];
#pragma unroll
    for (int o = 0; o < 8; ++o) {
        float acc = bias;
#pragma unroll
        for (int j = 0; j < 31; ++j) acc += win[o + j] * wr[j];
        out[((size_t)(t0 + o) * B_SZ + b) * 512 + c] = f2bf_(dswishf_(acc));
    }
}

__global__ __launch_bounds__(256) void norm_k(float* __restrict__ x)
{
    const int row = blockIdx.x * 4 + (threadIdx.x >> 6);
    const int lane = threadIdx.x & 63;
    float* r = x + (size_t)row * 512;
    float v[8];
    float ss = 0.f;
#pragma unroll
    for (int j = 0; j < 8; ++j) { v[j] = r[lane + (j << 6)]; ss += v[j] * v[j]; }
#pragma unroll
    for (int o = 32; o > 0; o >>= 1) ss += __shfl_xor(ss, o, 64);
    const float scale = rsqrtf(ss * (1.f / 512.f) + EPS_BN);
#pragma unroll
    for (int j = 0; j < 8; ++j) r[lane + (j << 6)] = v[j] * scale;
}

// ---------------------------------------------------------------------------
extern "C" void kernel_launch(void* const* d_in, const int* in_sizes, int n_in,
                              void* d_out, int out_size, void* d_ws, size_t ws_size,
                              hipStream_t stream)
{
    const float* src   = (const float*)d_in[0];
    const float* pos   = (const float*)d_in[1];
    const float* fm_w1 = (const float*)d_in[2];
    const float* fm_b1 = (const float*)d_in[3];
    const float* fm_w2 = (const float*)d_in[4];
    const float* fm_b2 = (const float*)d_in[5];
    const float* f_w1  = (const float*)d_in[6];
    const float* f_b1  = (const float*)d_in[7];
    const float* f_w2  = (const float*)d_in[8];
    const float* f_b2  = (const float*)d_in[9];
    const float* ipw   = (const float*)d_in[10];
    const float* ipb   = (const float*)d_in[11];
    const float* opw   = (const float*)d_in[12];
    const float* opb   = (const float*)d_in[13];
    const float* lpw   = (const float*)d_in[14];
    const float* pbu   = (const float*)d_in[15];
    const float* pbv   = (const float*)d_in[16];
    const float* cpw1  = (const float*)d_in[17];
    const float* cpb1  = (const float*)d_in[18];
    const float* cdw   = (const float*)d_in[19];
    const float* cdb   = (const float*)d_in[20];
    const float* cpw2  = (const float*)d_in[21];
    const float* cpb2  = (const float*)d_in[22];

    float* x = (float*)d_out;              // running activation (8192 x 512) f32

    // ---- workspace layout (~160 MB) ----
    char* base = (char*)d_ws;
    u16*   wb    = (u16*)base;   base += 6291456ull * 2;   // 9 weights bf16
    u16*   src_b = (u16*)base;   base += 4194304ull * 2;
    u16*   pos_b = (u16*)base;   base += 524288ull * 2;    // 1024x512 padded
    u16*   xb    = (u16*)base;   base += 4194304ull * 2;
    u16*   hb    = (u16*)base;   base += 16777216ull * 2;  // FFN hidden / c2b / dwconv out
    u16*   aob   = (u16*)base;   base += 4194304ull * 2;
    float* qkvb  = (float*)base; base += 12582912ull * 4;  // qkv / scores+probs / pw1+glu
    float* pm    = (float*)base; base += 524288ull * 4;
    u16*   qu_b  = (u16*)base;   base += 4194304ull * 2;
    u16*   qv_b  = (u16*)base;   base += 4194304ull * 2;
    u16*   k_b   = (u16*)base;   base += 4194304ull * 2;
    u16*   v_b   = (u16*)base;   base += 4194304ull * 2;
    u16*   p_b   = (u16*)base;   base += 524288ull * 2;    // [8][1024][64]
    float* wTd   = (float*)base; base += 15872ull * 4;

    u16*   c2b   = hb;                                   // 32x512x1024 bf16 (33.5 MB)
    float* sc    = qkvb;                                 // 32x512x512 f32 (33.5 MB)
    u16*   probs = (u16*)(qkvb + 8388608);               // 32x512x512 bf16 (16.8 MB)
    float* pw1_o = qkvb;                                 // 8192x1024 f32 (after attn)
    float* glu_o = qkvb + 8388608;                       // 8192x512 f32

    u16* fm_w1b = wb;
    u16* fm_w2b = wb + 1048576;
    u16* f_w1b  = wb + 2097152;
    u16* f_w2b  = wb + 3145728;
    u16* ipwb   = wb + 4194304;
    u16* opwb   = wb + 4980736;
    u16* lpwb   = wb + 5242880;
    u16* cpw1b  = wb + 5505024;
    u16* cpw2b  = wb + 6029312;

    const dim3 blk(256);

    // 0) f32 -> bf16 conversions
    WPtrs wp = {{fm_w1, fm_w2, f_w1, f_w2, ipw, opw, lpw, cpw1, cpw2}};
    cvt_w_k<<<dim3(6291456 / 1024), blk, 0, stream>>>(wp, wb);
    cvt_k<<<dim3(4194304 / 1024), blk, 0, stream>>>(src, src_b);
    cvt_pos_k<<<dim3(524288 / 1024), blk, 0, stream>>>(pos, pos_b);
    dwt_k<<<dim3(62), blk, 0, stream>>>(cdw, wTd);

    // 1) macaron FFN: x = src + W2 @ dswish(W1 @ src)
    gemm_mfma<1, false, false, true><<<dim3(16, 64), blk, 0, stream>>>(
        src_b, fm_w1b, fm_b1, nullptr, nullptr, hb, NROWS, 512, DFF_);
    gemm_mfma<0, true, true, true><<<dim3(4, 64), blk, 0, stream>>>(
        hb, fm_w2b, fm_b2, src, x, xb, NROWS, DFF_, 512);

    // 2) qkv and positional projections (f32 outputs), then bf16 repacks
    gemm_mfma<0, false, true, false><<<dim3(12, 64), blk, 0, stream>>>(
        xb, ipwb, ipb, nullptr, qkvb, nullptr, NROWS, 512, 1536);
    gemm_mfma<0, false, true, false><<<dim3(4, 8), blk, 0, stream>>>(
        pos_b, lpwb, nullptr, nullptr, pm, nullptr, 1024, 512, 512);
    repack_qkv<<<dim3(16384), blk, 0, stream>>>(qkvb, pbu, pbv, qu_b, qv_b, k_b, v_b);
    repack_p<<<dim3(2048), blk, 0, stream>>>(pm, p_b);

    // 3) MFMA rel-pos attention, chunked over batch (32 bh per chunk)
    for (int bc = 0; bc < B_SZ / BCHUNK; ++bc) {
        const int b0 = bc * BCHUNK;
        c2_mfma<<<dim3(8, 4, 32), blk, 0, stream>>>(qv_b, p_b, c2b, b0);
        scores_c1<<<dim3(4, 4, 32), blk, 0, stream>>>(qu_b, k_b, c2b, sc, b0);
        softmax_rows<<<dim3(32 * 512 / 4), blk, 0, stream>>>(sc, probs);
        pv_mfma<<<dim3(4, 32), blk, 0, stream>>>(probs, v_b, aob, b0);
    }

    // 4) out projection (residual into x)
    gemm_mfma<0, true, true, true><<<dim3(4, 64), blk, 0, stream>>>(
        aob, opwb, opb, x, x, xb, NROWS, 512, 512);

    // 5) conv module: pw1 -> GLU -> causal dwconv(+dswish, ->bf16) -> pw2 (residual)
    gemm_mfma<0, false, true, false><<<dim3(8, 64), blk, 0, stream>>>(
        xb, cpw1b, cpb1, nullptr, pw1_o, nullptr, NROWS, 512, 1024);
    glu_k<<<dim3(NROWS * 512 / 256), blk, 0, stream>>>(pw1_o, glu_o);
    dwconv_k<<<dim3(2048), blk, 0, stream>>>(glu_o, wTd, cdb, hb);
    gemm_mfma<0, true, true, true><<<dim3(4, 64), blk, 0, stream>>>(
        hb, cpw2b, cpb2, x, x, xb, NROWS, 512, 512);

    // 6) second FFN
    gemm_mfma<1, false, false, true><<<dim3(16, 64), blk, 0, stream>>>(
        xb, f_w1b, f_b1, nullptr, nullptr, hb, NROWS, 512, DFF_);
    gemm_mfma<0, true, true, false><<<dim3(4, 64), blk, 0, stream>>>(
        hb, f_w2b, f_b2, x, x, nullptr, NROWS, DFF_, 512);

    // 7) BasicNorm
    norm_k<<<dim3(NROWS / 4), blk, 0, stream>>>(x);
}